// Round 9
// baseline (407.416 us; speedup 1.0000x reference)
//
#include <hip/hip_runtime.h>

#define N_NODES 50000
#define N_EDGES 800000
#define D 128
#define NUM_GRAPHS 128

typedef __attribute__((ext_vector_type(8)))  short bfrag8;
typedef __attribute__((ext_vector_type(16))) float f32x16;
typedef __attribute__((ext_vector_type(4)))  int   intv4;

__device__ __forceinline__ float4 f4zero() { return make_float4(0.f, 0.f, 0.f, 0.f); }

__device__ __forceinline__ unsigned short f2bf(float f) {
    unsigned u = __float_as_uint(f);
    unsigned r = (u + 0x7fffu + ((u >> 16) & 1u)) >> 16;
    return (unsigned short)r;
}
__device__ __forceinline__ float bf2f(unsigned short b) {
    return __uint_as_float(((unsigned)b) << 16);
}
// accumulate 8 bf16 (packed uint4) with inline BN+ReLU:
// acc[j] += max(sa[j]*v + sb[j], flo).  flo=-3e38 => identity (no BN/ReLU).
__device__ __forceinline__ void acc8bn(float* a, uint4 r,
                                       const float* sa, const float* sb,
                                       float flo) {
    a[0] += fmaxf(fmaf(sa[0], __uint_as_float(r.x << 16),          sb[0]), flo);
    a[1] += fmaxf(fmaf(sa[1], __uint_as_float(r.x & 0xffff0000u), sb[1]), flo);
    a[2] += fmaxf(fmaf(sa[2], __uint_as_float(r.y << 16),          sb[2]), flo);
    a[3] += fmaxf(fmaf(sa[3], __uint_as_float(r.y & 0xffff0000u), sb[3]), flo);
    a[4] += fmaxf(fmaf(sa[4], __uint_as_float(r.z << 16),          sb[4]), flo);
    a[5] += fmaxf(fmaf(sa[5], __uint_as_float(r.z & 0xffff0000u), sb[5]), flo);
    a[6] += fmaxf(fmaf(sa[6], __uint_as_float(r.w << 16),          sb[6]), flo);
    a[7] += fmaxf(fmaf(sa[7], __uint_as_float(r.w & 0xffff0000u), sb[7]), flo);
}

// ===========================================================================
// prep: W->Wt (bf16 T), x->bf16, zero deg, zero stats (3x8x256), zero out,
// zero dummy rows of BOTH H buffers.  grid = 512+6250+196+24+64+1 = 7047
// ===========================================================================
__global__ __launch_bounds__(256) void prep_kernel(
    const float* __restrict__ W1, const float* __restrict__ W2,
    const float* __restrict__ x, short* __restrict__ Wt,
    ushort4* __restrict__ Hb, unsigned* __restrict__ HcDummy,
    int* __restrict__ deg, float* __restrict__ stats,
    float* __restrict__ outZero)
{
    int b = blockIdx.x, t = threadIdx.x;
    if (b < 512) {
        int idx = b * 256 + t;                 // 131072 = 8*128*128
        int m = idx >> 14, rem = idx & 16383;
        int k = rem >> 7, n = rem & 127;
        const float* W = (m < 4) ? (W1 + (size_t)m * 16384)
                                 : (W2 + (size_t)(m - 4) * 16384);
        Wt[(size_t)m * 16384 + n * 128 + k] = (short)f2bf(W[k * 128 + n]);
    } else if (b < 6762) {
        int i = (b - 512) * 256 + t;           // N*32 = 1,600,000 exactly
        float4 v = ((const float4*)x)[i];
        Hb[i] = make_ushort4(f2bf(v.x), f2bf(v.y), f2bf(v.z), f2bf(v.w));
    } else if (b < 6958) {
        int i = (b - 6762) * 256 + t;
        if (i < N_NODES) deg[i] = 0;
    } else if (b < 6982) {
        int i = (b - 6958) * 256 + t;          // 6144 floats: 3 x 8 x (sum||sq)
        stats[i] = 0.f;
    } else if (b < 7046) {
        int i = (b - 6982) * 256 + t;          // 16384 floats = out
        outZero[i] = 0.f;
    } else {
        // zero dummy row N_NODES of both H buffers (64 dwords each)
        if (t < 64)       ((unsigned*)Hb)[(size_t)N_NODES * 64 + t] = 0u;
        else if (t < 128) HcDummy[t - 64] = 0u;
    }
}

// ===========================================================================
// CSR build (padded to multiple of 8 per row, ushort entries)
// ===========================================================================
__global__ __launch_bounds__(256) void hist_kernel(
    const int* __restrict__ dst, int* __restrict__ deg,
    unsigned short* __restrict__ edge_pos)
{
    int e = blockIdx.x * 256 + threadIdx.x;
    if (e < N_EDGES) edge_pos[e] = (unsigned short)atomicAdd(&deg[dst[e]], 1);
}

__global__ __launch_bounds__(256) void scan_block_kernel(
    const int* __restrict__ deg, int* __restrict__ row_ptr,
    int* __restrict__ blockSum)
{
    __shared__ int wsum[4];
    int t = threadIdx.x, b = blockIdx.x;
    int i = b * 256 + t;
    int v = (i < N_NODES) ? ((deg[i] + 7) & ~7) : 0;   // padded degree
    int lane = t & 63, wid = t >> 6;
    #pragma unroll
    for (int off = 1; off < 64; off <<= 1) {
        int u = __shfl_up(v, off, 64);
        if (lane >= off) v += u;
    }
    if (lane == 63) wsum[wid] = v;
    __syncthreads();
    int add = 0;
    for (int w = 0; w < wid; ++w) add += wsum[w];
    v += add;
    if (i < N_NODES) row_ptr[i + 1] = v;
    if (t == 255) blockSum[b] = v;
}

__global__ __launch_bounds__(256) void scan_fixup_kernel(
    const int* __restrict__ blockSum, int* __restrict__ row_ptr, int nb)
{
    __shared__ int wsum[4];
    __shared__ int sbuf[256];
    int t = threadIdx.x, b = blockIdx.x;
    int v = (t < nb) ? blockSum[t] : 0;
    int lane = t & 63, wid = t >> 6;
    #pragma unroll
    for (int off = 1; off < 64; off <<= 1) {
        int u = __shfl_up(v, off, 64);
        if (lane >= off) v += u;
    }
    if (lane == 63) wsum[wid] = v;
    __syncthreads();
    int add = 0;
    for (int w = 0; w < wid; ++w) add += wsum[w];
    sbuf[t] = v + add;
    __syncthreads();
    if (b == 0 && t == 0) row_ptr[0] = 0;
    if (b > 0) {
        int off = sbuf[b - 1];
        int i = b * 256 + t;
        if (i < N_NODES) row_ptr[i + 1] += off;
    }
}

// edge fill (blocks [0,3125)) + pad-slot fill with dummy node (blocks >= 3125)
__global__ __launch_bounds__(256) void fill_kernel(
    const int* __restrict__ src, const int* __restrict__ dst,
    const int* __restrict__ row_ptr, const unsigned short* __restrict__ edge_pos,
    const int* __restrict__ deg, unsigned short* __restrict__ csr_src)
{
    int b = blockIdx.x, t = threadIdx.x;
    if (b < 3125) {
        int e = b * 256 + t;
        if (e < N_EDGES)
            csr_src[row_ptr[dst[e]] + (int)edge_pos[e]] = (unsigned short)src[e];
    } else {
        int n = (b - 3125) * 256 + t;
        if (n < N_NODES) {
            int e0 = row_ptr[n] + deg[n];
            int e1 = row_ptr[n + 1];
            for (int j = e0; j < e1; ++j)
                csr_src[j] = (unsigned short)N_NODES;
        }
    }
}

// ===========================================================================
// FUSED LAYER (64-row tile): prev-layer BN+ReLU applied inline during
// gather loads (no bnapply kernel), then
// z2 = (relu(A @ W1 + b1)) @ W2 + b2 via bf16 MFMA 32x32x16.
// Pad slots (dummy zero row) contribute max(sb,flo) each under inline BN;
// corrected analytically per row via deg[] (npad * max(sb,flo)).
// Hout stored non-temporally, csr read non-temporally: keep L2 for H-in.
// Hin != Hout (ping-pong). Stats striped 8x. Last layer: pool fused.
// ===========================================================================
__global__ __launch_bounds__(256, 4) void layer_kernel(
    const ushort* __restrict__ Hin,
    const int* __restrict__ row_ptr,
    const unsigned short* __restrict__ csr,
    const int* __restrict__ deg,
    const float* __restrict__ epsp,
    const float* __restrict__ statsPrev,   // prev layer [8][256] striped, or null
    const float* __restrict__ gammaP,
    const float* __restrict__ betaP,
    const short* __restrict__ Wt1,
    const short* __restrict__ Wt2,
    const float* __restrict__ bias1,
    const float* __restrict__ bias2,
    ushort* __restrict__ Hout,
    float* __restrict__ statsBase,     // this layer [8][256] striped, or null
    const int* __restrict__ batch,
    float* __restrict__ poolOut,
    int M)
{
    __shared__ __align__(16) short zlds[2][32 * 128]; // 16 KB (A / z1 / z2)
    __shared__ float ssum[128];
    __shared__ float ssq[128];
    __shared__ float salds[128];
    __shared__ float sblds[128];

    const int tid  = threadIdx.x;
    const int wv   = tid >> 6;
    const int lane = tid & 63;
    const int half = lane >> 5;
    const int ln   = lane & 31;
    const int rg   = wv & 1;
    const int ch   = wv >> 1;
    const int row0 = blockIdx.x * 64 + rg * 32;
    const bool doStats = (statsBase != nullptr);
    if (doStats && tid < 128) { ssum[tid] = 0.f; ssq[tid] = 0.f; }

    // ---- derive prev-layer BN scale/shift (identity if none) ----
    if (tid < 128) {
        float a = 1.f, bb = 0.f;
        if (statsPrev) {
            float s = 0.f, q = 0.f;
            #pragma unroll
            for (int k = 0; k < 8; ++k) {
                s += statsPrev[k * 256 + tid];
                q += statsPrev[k * 256 + 128 + tid];
            }
            const float invN = 1.0f / (float)N_NODES;
            float m = s * invN;
            a = gammaP[tid] * rsqrtf(q * invN - m * m + 1e-5f);
            bb = betaP[tid] - m * a;
        }
        salds[tid] = a;
        sblds[tid] = bb;
    }
    __syncthreads();   // S-1: sa/sb ready, ssum init

    const float flo = statsPrev ? 0.f : -3.0e38f;

    short* zw = &zlds[rg][0];

    // ---- Phase G: gather 64 rows into zlds in A-fragment layout ----
    {
        const uint4* H4 = (const uint4*)Hin;
        const float eps1 = 1.0f + *epsp;
        const int gl = tid & 15;              // chunk lane
        float sa8[8], sb8[8];
        #pragma unroll
        for (int j = 0; j < 8; ++j) {
            sa8[j] = salds[gl * 8 + j];
            sb8[j] = sblds[gl * 8 + j];
        }
        #pragma unroll
        for (int it = 0; it < 4; ++it) {
            int r = it * 16 + (tid >> 4);     // local row 0..63
            int node = blockIdx.x * 64 + r;
            float acc[8] = {0.f, 0.f, 0.f, 0.f, 0.f, 0.f, 0.f, 0.f};
            if (node < M) {
                // self term: (1+eps) * y(h[node])
                uint4 hv = H4[(size_t)node * 16 + gl];
                acc8bn(acc, hv, sa8, sb8, flo);
                #pragma unroll
                for (int j = 0; j < 8; ++j) acc[j] *= eps1;

                int beg = row_ptr[node], end = row_ptr[node + 1];
                int base = beg;
                int idx = (int)__builtin_nontemporal_load(&csr[base + gl]);
                while (base < end) {
                    int nb = base + 16;
                    int nidx = 0;
                    if (nb < end)
                        nidx = (int)__builtin_nontemporal_load(&csr[nb + gl]);
                    int cnt = end - base;          // multiple of 8
                    int s0 = __shfl(idx, 0, 16), s1 = __shfl(idx, 1, 16);
                    int s2 = __shfl(idx, 2, 16), s3 = __shfl(idx, 3, 16);
                    int s4 = __shfl(idx, 4, 16), s5 = __shfl(idx, 5, 16);
                    int s6 = __shfl(idx, 6, 16), s7 = __shfl(idx, 7, 16);
                    uint4 u0 = H4[(size_t)s0 * 16 + gl];
                    uint4 u1 = H4[(size_t)s1 * 16 + gl];
                    uint4 u2 = H4[(size_t)s2 * 16 + gl];
                    uint4 u3 = H4[(size_t)s3 * 16 + gl];
                    uint4 u4 = H4[(size_t)s4 * 16 + gl];
                    uint4 u5 = H4[(size_t)s5 * 16 + gl];
                    uint4 u6 = H4[(size_t)s6 * 16 + gl];
                    uint4 u7 = H4[(size_t)s7 * 16 + gl];
                    if (cnt > 8) {
                        int t0 = __shfl(idx,  8, 16), t1 = __shfl(idx,  9, 16);
                        int t2 = __shfl(idx, 10, 16), t3 = __shfl(idx, 11, 16);
                        int t4 = __shfl(idx, 12, 16), t5 = __shfl(idx, 13, 16);
                        int t6 = __shfl(idx, 14, 16), t7 = __shfl(idx, 15, 16);
                        uint4 w0 = H4[(size_t)t0 * 16 + gl];
                        uint4 w1 = H4[(size_t)t1 * 16 + gl];
                        uint4 w2 = H4[(size_t)t2 * 16 + gl];
                        uint4 w3 = H4[(size_t)t3 * 16 + gl];
                        uint4 w4 = H4[(size_t)t4 * 16 + gl];
                        uint4 w5 = H4[(size_t)t5 * 16 + gl];
                        uint4 w6 = H4[(size_t)t6 * 16 + gl];
                        uint4 w7 = H4[(size_t)t7 * 16 + gl];
                        acc8bn(acc, u0, sa8, sb8, flo); acc8bn(acc, u1, sa8, sb8, flo);
                        acc8bn(acc, u2, sa8, sb8, flo); acc8bn(acc, u3, sa8, sb8, flo);
                        acc8bn(acc, u4, sa8, sb8, flo); acc8bn(acc, u5, sa8, sb8, flo);
                        acc8bn(acc, u6, sa8, sb8, flo); acc8bn(acc, u7, sa8, sb8, flo);
                        acc8bn(acc, w0, sa8, sb8, flo); acc8bn(acc, w1, sa8, sb8, flo);
                        acc8bn(acc, w2, sa8, sb8, flo); acc8bn(acc, w3, sa8, sb8, flo);
                        acc8bn(acc, w4, sa8, sb8, flo); acc8bn(acc, w5, sa8, sb8, flo);
                        acc8bn(acc, w6, sa8, sb8, flo); acc8bn(acc, w7, sa8, sb8, flo);
                    } else {
                        acc8bn(acc, u0, sa8, sb8, flo); acc8bn(acc, u1, sa8, sb8, flo);
                        acc8bn(acc, u2, sa8, sb8, flo); acc8bn(acc, u3, sa8, sb8, flo);
                        acc8bn(acc, u4, sa8, sb8, flo); acc8bn(acc, u5, sa8, sb8, flo);
                        acc8bn(acc, u6, sa8, sb8, flo); acc8bn(acc, u7, sa8, sb8, flo);
                    }
                    idx = nidx; base = nb;
                }
                // pad correction: npad dummy-zero rows contributed max(sb,flo)
                int npad = (end - beg) - deg[node];
                if (npad > 0) {
                    float fp = (float)npad;
                    #pragma unroll
                    for (int j = 0; j < 8; ++j)
                        acc[j] -= fp * fmaxf(sb8[j], flo);
                }
            }
            uint4 o;
            o.x = (unsigned)f2bf(acc[0]) | ((unsigned)f2bf(acc[1]) << 16);
            o.y = (unsigned)f2bf(acc[2]) | ((unsigned)f2bf(acc[3]) << 16);
            o.z = (unsigned)f2bf(acc[4]) | ((unsigned)f2bf(acc[5]) << 16);
            o.w = (unsigned)f2bf(acc[6]) | ((unsigned)f2bf(acc[7]) << 16);
            int rl = r & 31;
            ((uint4*)&zlds[r >> 5][0])[rl * 16 + (gl ^ (rl & 15))] = o;
        }
    }
    __syncthreads();   // S0: A in zlds

    // ---- preload af (A frags) from zlds ----
    bfrag8 af[8];
    #pragma unroll
    for (int kk = 0; kk < 8; ++kk) {
        int c = kk * 2 + half;
        af[kk] = *(const bfrag8*)(zw + ln * 128 + ((c ^ (ln & 15)) << 3));
    }
    __syncthreads();   // S1: all af preloads done, zlds writable

    // ---- GEMM1: z1 = relu(A@W1 + b1) -> zlds; B direct from global ----
    {
        f32x16 acc[2];
        #pragma unroll
        for (int ci = 0; ci < 2; ++ci)
            #pragma unroll
            for (int r = 0; r < 16; ++r) acc[ci][r] = 0.f;

        const short* Wb = Wt1 + (size_t)(ch * 64 + ln) * 128 + half * 8;
        #pragma unroll
        for (int kk = 0; kk < 8; ++kk) {
            #pragma unroll
            for (int ci = 0; ci < 2; ++ci) {
                bfrag8 bf = *(const bfrag8*)(Wb + ci * 32 * 128 + kk * 16);
                acc[ci] = __builtin_amdgcn_mfma_f32_32x32x16_bf16(
                    af[kk], bf, acc[ci], 0, 0, 0);
            }
        }
        #pragma unroll
        for (int ci = 0; ci < 2; ++ci) {
            int col = (ch * 2 + ci) * 32 + ln;
            int cc = col >> 3, co = col & 7;
            float bv = bias1[col];
            #pragma unroll
            for (int r = 0; r < 16; ++r) {
                int rloc = (r & 3) + 8 * (r >> 2) + 4 * half;
                float v = fmaxf(acc[ci][r] + bv, 0.f);
                zw[rloc * 128 + ((cc ^ (rloc & 15)) << 3) + co] = (short)f2bf(v);
            }
        }
    }
    __syncthreads();   // S2: z1 complete

    // ---- preload af2 from zlds ----
    bfrag8 af2[8];
    #pragma unroll
    for (int kk = 0; kk < 8; ++kk) {
        int c = kk * 2 + half;
        af2[kk] = *(const bfrag8*)(zw + ln * 128 + ((c ^ (ln & 15)) << 3));
    }
    __syncthreads();   // S3: all af2 preloads done, zlds writable

    // ---- GEMM2: z2 = z1 @ W2 + b2 -> zlds; stats on fp32 values ----
    {
        f32x16 acc[2];
        #pragma unroll
        for (int ci = 0; ci < 2; ++ci)
            #pragma unroll
            for (int r = 0; r < 16; ++r) acc[ci][r] = 0.f;

        const short* Wb = Wt2 + (size_t)(ch * 64 + ln) * 128 + half * 8;
        #pragma unroll
        for (int kk = 0; kk < 8; ++kk) {
            #pragma unroll
            for (int ci = 0; ci < 2; ++ci) {
                bfrag8 bf = *(const bfrag8*)(Wb + ci * 32 * 128 + kk * 16);
                acc[ci] = __builtin_amdgcn_mfma_f32_32x32x16_bf16(
                    af2[kk], bf, acc[ci], 0, 0, 0);
            }
        }
        #pragma unroll
        for (int ci = 0; ci < 2; ++ci) {
            int col = (ch * 2 + ci) * 32 + ln;
            int cc = col >> 3, co = col & 7;
            float bv = bias2[col];
            float s = 0.f, sq = 0.f;
            #pragma unroll
            for (int r = 0; r < 16; ++r) {
                int rloc = (r & 3) + 8 * (r >> 2) + 4 * half;
                float v = acc[ci][r] + bv;
                zw[rloc * 128 + ((cc ^ (rloc & 15)) << 3) + co] = (short)f2bf(v);
                if (row0 + rloc < M) { s += v; sq += v * v; }
            }
            if (doStats) {
                s  += __shfl_xor(s, 32);
                sq += __shfl_xor(sq, 32);
                if (half == 0) {
                    atomicAdd(&ssum[col], s);
                    atomicAdd(&ssq[col], sq);
                }
            }
        }
    }
    __syncthreads();   // S4: z2 complete, ssum atomics done

    if (poolOut == nullptr) {
        // ---- coalesced non-temporal store: zlds -> Hout ----
        intv4* Ho = (intv4*)Hout;
        #pragma unroll
        for (int i = 0; i < 4; ++i) {
            int id = i * 256 + tid;            // 1024 int4
            int r = id >> 4, c = id & 15;
            int rl = r & 31;
            int grow = blockIdx.x * 64 + r;
            if (grow < M) {
                intv4 v = ((const intv4*)&zlds[r >> 5][0])[rl * 16 + (c ^ (rl & 15))];
                __builtin_nontemporal_store(v, &Ho[(size_t)grow * 16 + c]);
            }
        }
    } else {
        // ---- fused global_add_pool: sum rows by (sorted) batch id ----
        int c4 = tid & 31;                     // column quad c4*4..+3
        int rl8 = tid >> 5;                    // 8 row-lanes
        int cc = c4 >> 1, co = (c4 & 1) * 4;
        float4 ap = f4zero();
        int gcur = -1;
        for (int i = rl8; i < 64; i += 8) {
            int grow = blockIdx.x * 64 + i;
            if (grow >= M) break;
            int g = batch[grow];
            if (g != gcur) {
                if (gcur >= 0) {
                    float* o = poolOut + gcur * D + c4 * 4;
                    atomicAdd(o + 0, ap.x); atomicAdd(o + 1, ap.y);
                    atomicAdd(o + 2, ap.z); atomicAdd(o + 3, ap.w);
                }
                gcur = g; ap = f4zero();
            }
            const short* zr = &zlds[i >> 5][0];
            int rl = i & 31;
            const ushort4 u = *(const ushort4*)
                ((const ushort*)(zr + rl * 128 + ((cc ^ (rl & 15)) << 3) + co));
            ap.x += bf2f(u.x); ap.y += bf2f(u.y);
            ap.z += bf2f(u.z); ap.w += bf2f(u.w);
        }
        if (gcur >= 0) {
            float* o = poolOut + gcur * D + c4 * 4;
            atomicAdd(o + 0, ap.x); atomicAdd(o + 1, ap.y);
            atomicAdd(o + 2, ap.z); atomicAdd(o + 3, ap.w);
        }
    }
    if (doStats && tid < 128) {
        float* slot = statsBase + (size_t)(blockIdx.x & 7) * 256;
        atomicAdd(&slot[tid],       ssum[tid]);
        atomicAdd(&slot[128 + tid], ssq[tid]);
    }
}

extern "C" void kernel_launch(void* const* d_in, const int* in_sizes, int n_in,
                              void* d_out, int out_size, void* d_ws, size_t ws_size,
                              hipStream_t stream)
{
    const float* x     = (const float*)d_in[0];
    const int*   ei    = (const int*)d_in[1];
    const int*   batch = (const int*)d_in[2];
    const float* W1    = (const float*)d_in[3];
    const float* b1    = (const float*)d_in[4];
    const float* W2    = (const float*)d_in[5];
    const float* b2    = (const float*)d_in[6];
    const float* eps   = (const float*)d_in[7];
    const float* gamma = (const float*)d_in[8];
    const float* beta  = (const float*)d_in[9];
    float* out = (float*)d_out;

    // ---- workspace layout ----
    // Two H buffers, each [N+1][128] bf16 (row N = dummy zero row)
    unsigned short* Hb  = (unsigned short*)d_ws;              // [N+1,128] bf16
    unsigned short* Hc  = Hb + (size_t)(N_NODES + 1) * D;     // [N+1,128] bf16
    float* stats    = (float*)(Hc + (size_t)(N_NODES + 1) * D); // [3][8][256]
    int*   deg      = (int*)(stats + 3 * 2048);               // [N]
    int*   row_ptr  = deg + N_NODES;                          // [N+1]
    int*   blockSum = row_ptr + N_NODES + 1;                  // [256]
    unsigned short* edge_pos = (unsigned short*)(blockSum + 256);  // [E]
    unsigned short* csr_src  = edge_pos + N_EDGES;            // [E + 7N + 16]
    short* Wt       = (short*)(csr_src + N_EDGES + 7 * N_NODES + 16); // [8][128][128]

    const int* src = ei;
    const int* dst = ei + N_EDGES;

    const int edgeBlocks = (N_EDGES + 255) / 256;      // 3125
    const int scanBlocks = (N_NODES + 255) / 256;      // 196
    const int gemmBlocks = (N_NODES + 63) / 64;        // 782

    prep_kernel<<<7047, 256, 0, stream>>>(W1, W2, x, Wt, (ushort4*)Hb,
                                          (unsigned*)(Hc + (size_t)N_NODES * D),
                                          deg, stats, out);
    hist_kernel<<<edgeBlocks, 256, 0, stream>>>(dst, deg, edge_pos);
    scan_block_kernel<<<scanBlocks, 256, 0, stream>>>(deg, row_ptr, blockSum);
    scan_fixup_kernel<<<scanBlocks, 256, 0, stream>>>(blockSum, row_ptr, scanBlocks);
    fill_kernel<<<edgeBlocks + scanBlocks, 256, 0, stream>>>(
        src, dst, row_ptr, edge_pos, deg, csr_src);

    unsigned short* Hin  = Hb;
    unsigned short* HoutB = Hc;
    for (int layer = 0; layer < 4; ++layer) {
        const bool bn = (layer < 3);
        const float* statsPrev = (layer > 0) ? stats + (size_t)(layer - 1) * 2048
                                             : nullptr;
        int gl = (layer > 0) ? layer - 1 : 0;
        layer_kernel<<<gemmBlocks, 256, 0, stream>>>(
            Hin, row_ptr, csr_src, deg, eps + layer,
            statsPrev, gamma + (size_t)gl * D, beta + (size_t)gl * D,
            Wt + (size_t)layer * 16384, Wt + (size_t)(4 + layer) * 16384,
            b1 + (size_t)layer * D, b2 + (size_t)layer * D, HoutB,
            bn ? stats + (size_t)layer * 2048 : nullptr,
            bn ? nullptr : batch,
            bn ? nullptr : out, N_NODES);
        unsigned short* tmp = Hin; Hin = HoutB; HoutB = tmp;
    }
}

// Round 12
// 342.749 us; speedup vs baseline: 1.1887x; 1.1887x over previous
//
#include <hip/hip_runtime.h>

#define N_NODES 50000
#define N_EDGES 800000
#define D 128
#define NUM_GRAPHS 128

typedef __attribute__((ext_vector_type(8)))  short bfrag8;
typedef __attribute__((ext_vector_type(16))) float f32x16;

__device__ __forceinline__ float4 f4zero() { return make_float4(0.f, 0.f, 0.f, 0.f); }

__device__ __forceinline__ unsigned short f2bf(float f) {
    unsigned u = __float_as_uint(f);
    unsigned r = (u + 0x7fffu + ((u >> 16) & 1u)) >> 16;
    return (unsigned short)r;
}
__device__ __forceinline__ float bf2f(unsigned short b) {
    return __uint_as_float(((unsigned)b) << 16);
}
__device__ __forceinline__ void acc8(float* a, uint4 r) {
    a[0] += __uint_as_float(r.x << 16);
    a[1] += __uint_as_float(r.x & 0xffff0000u);
    a[2] += __uint_as_float(r.y << 16);
    a[3] += __uint_as_float(r.y & 0xffff0000u);
    a[4] += __uint_as_float(r.z << 16);
    a[5] += __uint_as_float(r.z & 0xffff0000u);
    a[6] += __uint_as_float(r.w << 16);
    a[7] += __uint_as_float(r.w & 0xffff0000u);
}

// ===========================================================================
// prep: W->Wt (bf16 T), x->bf16, zero deg, zero stats (3x8x256), zero out,
// zero dummy rows of BOTH H buffers.  grid = 512+6250+196+24+64+1 = 7047
// ===========================================================================
__global__ __launch_bounds__(256) void prep_kernel(
    const float* __restrict__ W1, const float* __restrict__ W2,
    const float* __restrict__ x, short* __restrict__ Wt,
    ushort4* __restrict__ Hb, unsigned* __restrict__ HcDummy,
    int* __restrict__ deg, float* __restrict__ stats,
    float* __restrict__ outZero)
{
    int b = blockIdx.x, t = threadIdx.x;
    if (b < 512) {
        int idx = b * 256 + t;                 // 131072 = 8*128*128
        int m = idx >> 14, rem = idx & 16383;
        int k = rem >> 7, n = rem & 127;
        const float* W = (m < 4) ? (W1 + (size_t)m * 16384)
                                 : (W2 + (size_t)(m - 4) * 16384);
        Wt[(size_t)m * 16384 + n * 128 + k] = (short)f2bf(W[k * 128 + n]);
    } else if (b < 6762) {
        int i = (b - 512) * 256 + t;           // N*32 = 1,600,000 exactly
        float4 v = ((const float4*)x)[i];
        Hb[i] = make_ushort4(f2bf(v.x), f2bf(v.y), f2bf(v.z), f2bf(v.w));
    } else if (b < 6958) {
        int i = (b - 6762) * 256 + t;
        if (i < N_NODES) deg[i] = 0;
    } else if (b < 6982) {
        int i = (b - 6958) * 256 + t;          // 6144 floats: 3 x 8 x (sum||sq)
        stats[i] = 0.f;
    } else if (b < 7046) {
        int i = (b - 6982) * 256 + t;          // 16384 floats = out
        outZero[i] = 0.f;
    } else {
        // zero dummy row N_NODES of both H buffers (64 dwords each)
        if (t < 64)       ((unsigned*)Hb)[(size_t)N_NODES * 64 + t] = 0u;
        else if (t < 128) HcDummy[t - 64] = 0u;
    }
}

// ===========================================================================
// CSR build (padded to multiple of 8 per row, ushort entries)
// ===========================================================================
__global__ __launch_bounds__(256) void hist_kernel(
    const int* __restrict__ dst, int* __restrict__ deg,
    unsigned short* __restrict__ edge_pos)
{
    int e = blockIdx.x * 256 + threadIdx.x;
    if (e < N_EDGES) edge_pos[e] = (unsigned short)atomicAdd(&deg[dst[e]], 1);
}

__global__ __launch_bounds__(256) void scan_block_kernel(
    const int* __restrict__ deg, int* __restrict__ row_ptr,
    int* __restrict__ blockSum)
{
    __shared__ int wsum[4];
    int t = threadIdx.x, b = blockIdx.x;
    int i = b * 256 + t;
    int v = (i < N_NODES) ? ((deg[i] + 7) & ~7) : 0;   // padded degree
    int lane = t & 63, wid = t >> 6;
    #pragma unroll
    for (int off = 1; off < 64; off <<= 1) {
        int u = __shfl_up(v, off, 64);
        if (lane >= off) v += u;
    }
    if (lane == 63) wsum[wid] = v;
    __syncthreads();
    int add = 0;
    for (int w = 0; w < wid; ++w) add += wsum[w];
    v += add;
    if (i < N_NODES) row_ptr[i + 1] = v;
    if (t == 255) blockSum[b] = v;
}

__global__ __launch_bounds__(256) void scan_fixup_kernel(
    const int* __restrict__ blockSum, int* __restrict__ row_ptr, int nb)
{
    __shared__ int wsum[4];
    __shared__ int sbuf[256];
    int t = threadIdx.x, b = blockIdx.x;
    int v = (t < nb) ? blockSum[t] : 0;
    int lane = t & 63, wid = t >> 6;
    #pragma unroll
    for (int off = 1; off < 64; off <<= 1) {
        int u = __shfl_up(v, off, 64);
        if (lane >= off) v += u;
    }
    if (lane == 63) wsum[wid] = v;
    __syncthreads();
    int add = 0;
    for (int w = 0; w < wid; ++w) add += wsum[w];
    sbuf[t] = v + add;
    __syncthreads();
    if (b == 0 && t == 0) row_ptr[0] = 0;
    if (b > 0) {
        int off = sbuf[b - 1];
        int i = b * 256 + t;
        if (i < N_NODES) row_ptr[i + 1] += off;
    }
}

// edge fill (blocks [0,3125)) + pad-slot fill with dummy node (blocks >= 3125)
__global__ __launch_bounds__(256) void fill_kernel(
    const int* __restrict__ src, const int* __restrict__ dst,
    const int* __restrict__ row_ptr, const unsigned short* __restrict__ edge_pos,
    const int* __restrict__ deg, unsigned short* __restrict__ csr_src)
{
    int b = blockIdx.x, t = threadIdx.x;
    if (b < 3125) {
        int e = b * 256 + t;
        if (e < N_EDGES)
            csr_src[row_ptr[dst[e]] + (int)edge_pos[e]] = (unsigned short)src[e];
    } else {
        int n = (b - 3125) * 256 + t;
        if (n < N_NODES) {
            int e0 = row_ptr[n] + deg[n];
            int e1 = row_ptr[n + 1];
            for (int j = e0; j < e1; ++j)
                csr_src[j] = (unsigned short)N_NODES;
        }
    }
}

// ===========================================================================
// bnapply: H <- relu(bn(H)) in-place.  stats = layer base [8][256] striped.
// ===========================================================================
__global__ __launch_bounds__(256) void bnapply_kernel(
    uint4* __restrict__ H, const float* __restrict__ stats,
    const float* __restrict__ gamma, const float* __restrict__ beta)
{
    __shared__ float sa[128], sb[128];
    int tid = threadIdx.x;
    if (tid < 128) {
        float s = 0.f, q = 0.f;
        #pragma unroll
        for (int k = 0; k < 8; ++k) {
            s += stats[k * 256 + tid];
            q += stats[k * 256 + 128 + tid];
        }
        const float invN = 1.0f / (float)N_NODES;
        float m = s * invN;
        float a = gamma[tid] * rsqrtf(q * invN - m * m + 1e-5f);
        sa[tid] = a;
        sb[tid] = beta[tid] - m * a;
    }
    __syncthreads();
    int id = blockIdx.x * 256 + tid;          // [0, 800000)
    int c0 = (id & 15) * 8;
    uint4 u = H[id];
    float lo, hi;
    lo = fmaxf(sa[c0 + 0] * __uint_as_float(u.x << 16)          + sb[c0 + 0], 0.f);
    hi = fmaxf(sa[c0 + 1] * __uint_as_float(u.x & 0xffff0000u) + sb[c0 + 1], 0.f);
    u.x = (unsigned)f2bf(lo) | ((unsigned)f2bf(hi) << 16);
    lo = fmaxf(sa[c0 + 2] * __uint_as_float(u.y << 16)          + sb[c0 + 2], 0.f);
    hi = fmaxf(sa[c0 + 3] * __uint_as_float(u.y & 0xffff0000u) + sb[c0 + 3], 0.f);
    u.y = (unsigned)f2bf(lo) | ((unsigned)f2bf(hi) << 16);
    lo = fmaxf(sa[c0 + 4] * __uint_as_float(u.z << 16)          + sb[c0 + 4], 0.f);
    hi = fmaxf(sa[c0 + 5] * __uint_as_float(u.z & 0xffff0000u) + sb[c0 + 5], 0.f);
    u.z = (unsigned)f2bf(lo) | ((unsigned)f2bf(hi) << 16);
    lo = fmaxf(sa[c0 + 6] * __uint_as_float(u.w << 16)          + sb[c0 + 6], 0.f);
    hi = fmaxf(sa[c0 + 7] * __uint_as_float(u.w & 0xffff0000u) + sb[c0 + 7], 0.f);
    u.w = (unsigned)f2bf(lo) | ((unsigned)f2bf(hi) << 16);
    H[id] = u;
}

// ===========================================================================
// FUSED LAYER: gather 64 rows -> zlds (A layout), then
// z2 = (relu(A @ W1 + b1)) @ W2 + b2 via bf16 MFMA 32x32x16.
// Hin != Hout (ping-pong; fused kernel reads random rows of Hin while
// writing Hout). A never touches global memory.
// Stats striped 8x by blockIdx. Last layer: pool fused, no Hout store.
// ===========================================================================
__global__ __launch_bounds__(256, 3) void layer_kernel(
    const ushort* __restrict__ Hin,
    const int* __restrict__ row_ptr,
    const unsigned short* __restrict__ csr,
    const float* __restrict__ epsp,
    const short* __restrict__ Wt1,
    const short* __restrict__ Wt2,
    const float* __restrict__ bias1,
    const float* __restrict__ bias2,
    ushort* __restrict__ Hout,
    float* __restrict__ statsBase,     // [8][256] striped, or null
    const int* __restrict__ batch,
    float* __restrict__ poolOut,
    int M)
{
    __shared__ __align__(16) short Wlds[128 * 128];   // 32 KB
    __shared__ __align__(16) short zlds[2][32 * 128]; // 16 KB (A / z1 / z2)
    __shared__ float ssum[128];
    __shared__ float ssq[128];

    const int tid  = threadIdx.x;
    const int wv   = tid >> 6;
    const int lane = tid & 63;
    const int half = lane >> 5;
    const int ln   = lane & 31;
    const int rg   = wv & 1;
    const int ch   = wv >> 1;
    const int row0 = blockIdx.x * 64 + rg * 32;
    const bool doStats = (statsBase != nullptr);
    if (doStats && tid < 128) { ssum[tid] = 0.f; ssq[tid] = 0.f; }

    short* zw = &zlds[rg][0];

    // ---- Phase G: gather 64 rows into zlds in A-fragment layout ----
    {
        const uint4* H4 = (const uint4*)Hin;
        const float eps1 = 1.0f + *epsp;
        const int gl = tid & 15;              // chunk lane
        #pragma unroll
        for (int it = 0; it < 4; ++it) {
            int r = it * 16 + (tid >> 4);     // local row 0..63
            int node = blockIdx.x * 64 + r;
            float acc[8] = {0.f, 0.f, 0.f, 0.f, 0.f, 0.f, 0.f, 0.f};
            if (node < M) {
                uint4 hv = H4[(size_t)node * 16 + gl];
                acc[0] = eps1 * __uint_as_float(hv.x << 16);
                acc[1] = eps1 * __uint_as_float(hv.x & 0xffff0000u);
                acc[2] = eps1 * __uint_as_float(hv.y << 16);
                acc[3] = eps1 * __uint_as_float(hv.y & 0xffff0000u);
                acc[4] = eps1 * __uint_as_float(hv.z << 16);
                acc[5] = eps1 * __uint_as_float(hv.z & 0xffff0000u);
                acc[6] = eps1 * __uint_as_float(hv.w << 16);
                acc[7] = eps1 * __uint_as_float(hv.w & 0xffff0000u);
                int beg = row_ptr[node], end = row_ptr[node + 1];
                int base = beg;
                int idx = (int)csr[base + gl];     // +16 slack allocated
                while (base < end) {
                    int nb = base + 16;
                    int nidx = 0;
                    if (nb < end) nidx = (int)csr[nb + gl];
                    int cnt = end - base;          // multiple of 8
                    int s0 = __shfl(idx, 0, 16), s1 = __shfl(idx, 1, 16);
                    int s2 = __shfl(idx, 2, 16), s3 = __shfl(idx, 3, 16);
                    int s4 = __shfl(idx, 4, 16), s5 = __shfl(idx, 5, 16);
                    int s6 = __shfl(idx, 6, 16), s7 = __shfl(idx, 7, 16);
                    uint4 u0 = H4[(size_t)s0 * 16 + gl];
                    uint4 u1 = H4[(size_t)s1 * 16 + gl];
                    uint4 u2 = H4[(size_t)s2 * 16 + gl];
                    uint4 u3 = H4[(size_t)s3 * 16 + gl];
                    uint4 u4 = H4[(size_t)s4 * 16 + gl];
                    uint4 u5 = H4[(size_t)s5 * 16 + gl];
                    uint4 u6 = H4[(size_t)s6 * 16 + gl];
                    uint4 u7 = H4[(size_t)s7 * 16 + gl];
                    if (cnt > 8) {
                        int t0 = __shfl(idx,  8, 16), t1 = __shfl(idx,  9, 16);
                        int t2 = __shfl(idx, 10, 16), t3 = __shfl(idx, 11, 16);
                        int t4 = __shfl(idx, 12, 16), t5 = __shfl(idx, 13, 16);
                        int t6 = __shfl(idx, 14, 16), t7 = __shfl(idx, 15, 16);
                        uint4 w0 = H4[(size_t)t0 * 16 + gl];
                        uint4 w1 = H4[(size_t)t1 * 16 + gl];
                        uint4 w2 = H4[(size_t)t2 * 16 + gl];
                        uint4 w3 = H4[(size_t)t3 * 16 + gl];
                        uint4 w4 = H4[(size_t)t4 * 16 + gl];
                        uint4 w5 = H4[(size_t)t5 * 16 + gl];
                        uint4 w6 = H4[(size_t)t6 * 16 + gl];
                        uint4 w7 = H4[(size_t)t7 * 16 + gl];
                        acc8(acc, u0); acc8(acc, u1); acc8(acc, u2); acc8(acc, u3);
                        acc8(acc, u4); acc8(acc, u5); acc8(acc, u6); acc8(acc, u7);
                        acc8(acc, w0); acc8(acc, w1); acc8(acc, w2); acc8(acc, w3);
                        acc8(acc, w4); acc8(acc, w5); acc8(acc, w6); acc8(acc, w7);
                    } else {
                        acc8(acc, u0); acc8(acc, u1); acc8(acc, u2); acc8(acc, u3);
                        acc8(acc, u4); acc8(acc, u5); acc8(acc, u6); acc8(acc, u7);
                    }
                    idx = nidx; base = nb;
                }
            }
            uint4 o;
            o.x = (unsigned)f2bf(acc[0]) | ((unsigned)f2bf(acc[1]) << 16);
            o.y = (unsigned)f2bf(acc[2]) | ((unsigned)f2bf(acc[3]) << 16);
            o.z = (unsigned)f2bf(acc[4]) | ((unsigned)f2bf(acc[5]) << 16);
            o.w = (unsigned)f2bf(acc[6]) | ((unsigned)f2bf(acc[7]) << 16);
            int rl = r & 31;
            ((uint4*)&zlds[r >> 5][0])[rl * 16 + (gl ^ (rl & 15))] = o;
        }
    }
    __syncthreads();   // S0: A in zlds, ssum init

    // ---- preload af (A frags) from zlds; stage W1 -> Wlds ----
    bfrag8 af[8];
    #pragma unroll
    for (int kk = 0; kk < 8; ++kk) {
        int c = kk * 2 + half;
        af[kk] = *(const bfrag8*)(zw + ln * 128 + ((c ^ (ln & 15)) << 3));
    }
    {
        const int4* Wg = (const int4*)Wt1;
        int4* Wl = (int4*)Wlds;
        #pragma unroll
        for (int i = 0; i < 8; ++i) {
            int id = i * 256 + tid;            // 2048 int4
            int n = id >> 4, c = id & 15;
            Wl[n * 16 + (c ^ (n & 15))] = Wg[id];
        }
    }
    __syncthreads();   // S1: W1 staged, af preloads done

    // ---- GEMM1: z1 = relu(A@W1 + b1) -> zlds ----
    {
        f32x16 acc[2];
        #pragma unroll
        for (int ci = 0; ci < 2; ++ci)
            #pragma unroll
            for (int r = 0; r < 16; ++r) acc[ci][r] = 0.f;

        #pragma unroll
        for (int kk = 0; kk < 8; ++kk) {
            #pragma unroll
            for (int ci = 0; ci < 2; ++ci) {
                int n = (ch * 2 + ci) * 32 + ln;
                int c = kk * 2 + half;
                bfrag8 bf = *(const bfrag8*)(Wlds + n * 128 + ((c ^ (n & 15)) << 3));
                acc[ci] = __builtin_amdgcn_mfma_f32_32x32x16_bf16(
                    af[kk], bf, acc[ci], 0, 0, 0);
            }
        }
        #pragma unroll
        for (int ci = 0; ci < 2; ++ci) {
            int col = (ch * 2 + ci) * 32 + ln;
            int cc = col >> 3, co = col & 7;
            float bv = bias1[col];
            #pragma unroll
            for (int r = 0; r < 16; ++r) {
                int rloc = (r & 3) + 8 * (r >> 2) + 4 * half;
                float v = fmaxf(acc[ci][r] + bv, 0.f);
                zw[rloc * 128 + ((cc ^ (rloc & 15)) << 3) + co] = (short)f2bf(v);
            }
        }
    }
    __syncthreads();   // S2: z1 complete, G1 Wlds/zlds reads done

    // ---- stage W2 -> Wlds; preload af2 from zlds ----
    bfrag8 af2[8];
    #pragma unroll
    for (int kk = 0; kk < 8; ++kk) {
        int c = kk * 2 + half;
        af2[kk] = *(const bfrag8*)(zw + ln * 128 + ((c ^ (ln & 15)) << 3));
    }
    {
        const int4* Wg = (const int4*)Wt2;
        int4* Wl = (int4*)Wlds;
        #pragma unroll
        for (int i = 0; i < 8; ++i) {
            int id = i * 256 + tid;
            int n = id >> 4, c = id & 15;
            Wl[n * 16 + (c ^ (n & 15))] = Wg[id];
        }
    }
    __syncthreads();   // S3: W2 staged, all af2 preloads done

    // ---- GEMM2: z2 = z1 @ W2 + b2 -> zlds; stats on fp32 values ----
    {
        f32x16 acc[2];
        #pragma unroll
        for (int ci = 0; ci < 2; ++ci)
            #pragma unroll
            for (int r = 0; r < 16; ++r) acc[ci][r] = 0.f;

        #pragma unroll
        for (int kk = 0; kk < 8; ++kk) {
            #pragma unroll
            for (int ci = 0; ci < 2; ++ci) {
                int n = (ch * 2 + ci) * 32 + ln;
                int c = kk * 2 + half;
                bfrag8 bf = *(const bfrag8*)(Wlds + n * 128 + ((c ^ (n & 15)) << 3));
                acc[ci] = __builtin_amdgcn_mfma_f32_32x32x16_bf16(
                    af2[kk], bf, acc[ci], 0, 0, 0);
            }
        }
        #pragma unroll
        for (int ci = 0; ci < 2; ++ci) {
            int col = (ch * 2 + ci) * 32 + ln;
            int cc = col >> 3, co = col & 7;
            float bv = bias2[col];
            float s = 0.f, sq = 0.f;
            #pragma unroll
            for (int r = 0; r < 16; ++r) {
                int rloc = (r & 3) + 8 * (r >> 2) + 4 * half;
                float v = acc[ci][r] + bv;
                zw[rloc * 128 + ((cc ^ (rloc & 15)) << 3) + co] = (short)f2bf(v);
                if (row0 + rloc < M) { s += v; sq += v * v; }
            }
            if (doStats) {
                s  += __shfl_xor(s, 32);
                sq += __shfl_xor(sq, 32);
                if (half == 0) {
                    atomicAdd(&ssum[col], s);
                    atomicAdd(&ssq[col], sq);
                }
            }
        }
    }
    __syncthreads();   // S4: z2 complete, ssum atomics done

    if (poolOut == nullptr) {
        // ---- coalesced store: zlds -> Hout (64 rows x 16 int4) ----
        int4* Ho = (int4*)Hout;
        #pragma unroll
        for (int i = 0; i < 4; ++i) {
            int id = i * 256 + tid;            // 1024 int4
            int r = id >> 4, c = id & 15;
            int rl = r & 31;
            int grow = blockIdx.x * 64 + r;
            if (grow < M)
                Ho[(size_t)grow * 16 + c] =
                    ((const int4*)&zlds[r >> 5][0])[rl * 16 + (c ^ (rl & 15))];
        }
    } else {
        // ---- fused global_add_pool: sum rows by (sorted) batch id ----
        int c4 = tid & 31;                     // column quad c4*4..+3
        int rl8 = tid >> 5;                    // 8 row-lanes
        int cc = c4 >> 1, co = (c4 & 1) * 4;
        float4 ap = f4zero();
        int gcur = -1;
        for (int i = rl8; i < 64; i += 8) {
            int grow = blockIdx.x * 64 + i;
            if (grow >= M) break;
            int g = batch[grow];
            if (g != gcur) {
                if (gcur >= 0) {
                    float* o = poolOut + gcur * D + c4 * 4;
                    atomicAdd(o + 0, ap.x); atomicAdd(o + 1, ap.y);
                    atomicAdd(o + 2, ap.z); atomicAdd(o + 3, ap.w);
                }
                gcur = g; ap = f4zero();
            }
            const short* zr = &zlds[i >> 5][0];
            int rl = i & 31;
            const ushort4 u = *(const ushort4*)
                ((const ushort*)(zr + rl * 128 + ((cc ^ (rl & 15)) << 3) + co));
            ap.x += bf2f(u.x); ap.y += bf2f(u.y);
            ap.z += bf2f(u.z); ap.w += bf2f(u.w);
        }
        if (gcur >= 0) {
            float* o = poolOut + gcur * D + c4 * 4;
            atomicAdd(o + 0, ap.x); atomicAdd(o + 1, ap.y);
            atomicAdd(o + 2, ap.z); atomicAdd(o + 3, ap.w);
        }
    }
    if (doStats && tid < 128) {
        float* slot = statsBase + (size_t)(blockIdx.x & 7) * 256;
        atomicAdd(&slot[tid],       ssum[tid]);
        atomicAdd(&slot[128 + tid], ssq[tid]);
    }
}

extern "C" void kernel_launch(void* const* d_in, const int* in_sizes, int n_in,
                              void* d_out, int out_size, void* d_ws, size_t ws_size,
                              hipStream_t stream)
{
    const float* x     = (const float*)d_in[0];
    const int*   ei    = (const int*)d_in[1];
    const int*   batch = (const int*)d_in[2];
    const float* W1    = (const float*)d_in[3];
    const float* b1    = (const float*)d_in[4];
    const float* W2    = (const float*)d_in[5];
    const float* b2    = (const float*)d_in[6];
    const float* eps   = (const float*)d_in[7];
    const float* gamma = (const float*)d_in[8];
    const float* beta  = (const float*)d_in[9];
    float* out = (float*)d_out;

    // ---- workspace layout ----
    // Two H buffers, each [N+1][128] bf16 (row N = dummy zero row)
    unsigned short* Hb  = (unsigned short*)d_ws;              // [N+1,128] bf16
    unsigned short* Hc  = Hb + (size_t)(N_NODES + 1) * D;     // [N+1,128] bf16
    float* stats    = (float*)(Hc + (size_t)(N_NODES + 1) * D); // [3][8][256]
    int*   deg      = (int*)(stats + 3 * 2048);               // [N]
    int*   row_ptr  = deg + N_NODES;                          // [N+1]
    int*   blockSum = row_ptr + N_NODES + 1;                  // [256]
    unsigned short* edge_pos = (unsigned short*)(blockSum + 256);  // [E]
    unsigned short* csr_src  = edge_pos + N_EDGES;            // [E + 7N + 16]
    short* Wt       = (short*)(csr_src + N_EDGES + 7 * N_NODES + 16); // [8][128][128]

    const int* src = ei;
    const int* dst = ei + N_EDGES;

    const int edgeBlocks = (N_EDGES + 255) / 256;      // 3125
    const int scanBlocks = (N_NODES + 255) / 256;      // 196
    const int bnBlocks   = (N_NODES * 16) / 256;       // 3125 exact
    const int gemmBlocks = (N_NODES + 63) / 64;        // 782

    prep_kernel<<<7047, 256, 0, stream>>>(W1, W2, x, Wt, (ushort4*)Hb,
                                          (unsigned*)(Hc + (size_t)N_NODES * D),
                                          deg, stats, out);
    hist_kernel<<<edgeBlocks, 256, 0, stream>>>(dst, deg, edge_pos);
    scan_block_kernel<<<scanBlocks, 256, 0, stream>>>(deg, row_ptr, blockSum);
    scan_fixup_kernel<<<scanBlocks, 256, 0, stream>>>(blockSum, row_ptr, scanBlocks);
    fill_kernel<<<edgeBlocks + scanBlocks, 256, 0, stream>>>(
        src, dst, row_ptr, edge_pos, deg, csr_src);

    unsigned short* Hin  = Hb;
    unsigned short* HoutB = Hc;
    for (int layer = 0; layer < 4; ++layer) {
        const bool bn = (layer < 3);
        if (layer > 0) {
            bnapply_kernel<<<bnBlocks, 256, 0, stream>>>(
                (uint4*)Hin, stats + (size_t)(layer - 1) * 2048,
                gamma + (size_t)(layer - 1) * D, beta + (size_t)(layer - 1) * D);
        }
        layer_kernel<<<gemmBlocks, 256, 0, stream>>>(
            Hin, row_ptr, csr_src, eps + layer,
            Wt + (size_t)layer * 16384, Wt + (size_t)(4 + layer) * 16384,
            b1 + (size_t)layer * D, b2 + (size_t)layer * D, HoutB,
            bn ? stats + (size_t)layer * 2048 : nullptr,
            bn ? nullptr : batch,
            bn ? nullptr : out, N_NODES);
        unsigned short* tmp = Hin; Hin = HoutB; HoutB = tmp;
    }
}